// Round 12
// baseline (215.308 us; speedup 1.0000x reference)
//
#include <hip/hip_runtime.h>
#include <float.h>

#define NPRED 8192
#define NGT   32768
#define GRIDN 16
#define NCELL (GRIDN * GRIDN * GRIDN)    // 4096
#define BOUNDF 4.5f
#define CSIZE  0.5625f                   // 9/16, exact in fp32
#define INVC   1.7777778f
#define QBLK 256
#define NQB  ((NPRED * 8) / QBLK)        // 256 query blocks (8 lanes per query)

// ws layout (all offsets in bytes):
//   gcnt    u32[NCELL]        @ 0
//   gofs    u32[NCELL]        @ 16384
//   gstart  u32[NCELL+1]      @ 32768
//   gpts    float4[NGT]       @ 49664   (x,y,z, bitcast(orig gt idx))
//   bsums   u64[NQB]          @ 573952
//   counter u32               @ 576000

__device__ __forceinline__ int cellco(float v) {
    int c = (int)floorf((v + BOUNDF) * INVC);
    return min(GRIDN - 1, max(0, c));
}

__global__ void zero_kernel(unsigned int* __restrict__ gcnt, unsigned int* __restrict__ gofs,
                            unsigned int* __restrict__ counter) {
    int i = blockIdx.x * blockDim.x + threadIdx.x;
    if (i < NCELL) { gcnt[i] = 0u; gofs[i] = 0u; }
    if (i == 0) *counter = 0u;
}

__global__ void hist_kernel(const float* __restrict__ gt, unsigned int* __restrict__ gcnt) {
    int j = blockIdx.x * blockDim.x + threadIdx.x;
    if (j < NGT) {
        const float* g = gt + (size_t)j * 6;
        int c = (cellco(g[2]) * GRIDN + cellco(g[1])) * GRIDN + cellco(g[0]);
        atomicAdd(&gcnt[c], 1u);
    }
}

__global__ __launch_bounds__(1024) void scan_kernel(const unsigned int* __restrict__ gcnt,
                                                    unsigned int* __restrict__ gstart) {
    __shared__ unsigned int part[1024];
    const int t = threadIdx.x;
    unsigned int c0 = gcnt[4 * t + 0], c1 = gcnt[4 * t + 1];
    unsigned int c2 = gcnt[4 * t + 2], c3 = gcnt[4 * t + 3];
    unsigned int s = c0 + c1 + c2 + c3;
    part[t] = s;
    __syncthreads();
    for (int off = 1; off < 1024; off <<= 1) {   // Hillis-Steele inclusive scan
        unsigned int v = (t >= off) ? part[t - off] : 0u;
        __syncthreads();
        part[t] += v;
        __syncthreads();
    }
    unsigned int excl = (t > 0) ? part[t - 1] : 0u;
    gstart[4 * t + 0] = excl;
    gstart[4 * t + 1] = excl + c0;
    gstart[4 * t + 2] = excl + c0 + c1;
    gstart[4 * t + 3] = excl + c0 + c1 + c2;
    if (t == 1023) gstart[NCELL] = excl + s;     // == NGT
}

__global__ void scatter_kernel(const float* __restrict__ gt, const unsigned int* __restrict__ gstart,
                               unsigned int* __restrict__ gofs, float4* __restrict__ gpts) {
    int j = blockIdx.x * blockDim.x + threadIdx.x;
    if (j < NGT) {
        const float* g = gt + (size_t)j * 6;
        float x = g[0], y = g[1], z = g[2];
        int c = (cellco(z) * GRIDN + cellco(y)) * GRIDN + cellco(x);
        unsigned int pos = gstart[c] + atomicAdd(&gofs[c], 1u);
        gpts[pos] = make_float4(x, y, z, __uint_as_float((unsigned int)j));
    }
}

__global__ __launch_bounds__(QBLK) void query_kernel(const float* __restrict__ pred,
                                                     const float* __restrict__ gt,
                                                     const unsigned int* __restrict__ gstart,
                                                     const float4* __restrict__ gpts,
                                                     unsigned long long* __restrict__ bsums,
                                                     unsigned int* __restrict__ counter,
                                                     float* __restrict__ out) {
    const int tid = blockIdx.x * QBLK + threadIdx.x;
    const int q   = tid >> 3;                    // one query per 8-lane team, original order
    const int tl  = threadIdx.x & 7;
    const float* p = pred + (size_t)q * 6;
    const float qx = p[0], qy = p[1], qz = p[2];
    const int cx = cellco(qx), cy = cellco(qy), cz = cellco(qz);

    float bestd2 = FLT_MAX;
    unsigned long long best = 0xFFFFFFFFFFFFFFFFull;

    for (int r = 0; r <= GRIDN - 1; ++r) {
        if (r >= 1) {
            // team-min of bestd2 (uniform within 8-lane team after xor-reduce)
            float tmin = bestd2;
            tmin = fminf(tmin, __shfl_xor(tmin, 1));
            tmin = fminf(tmin, __shfl_xor(tmin, 2));
            tmin = fminf(tmin, __shfl_xor(tmin, 4));
            float lb = (float)(r - 1) * CSIZE;   // safe LB for any cell at Chebyshev r
            if (tmin < lb * lb * 0.999f) break;  // 0.999: conservative vs fp rounding
        }
        for (int dz = -r; dz <= r; ++dz) {
            int zc = cz + dz; if (zc < 0 || zc >= GRIDN) continue;
            for (int dy = -r; dy <= r; ++dy) {
                int yc = cy + dy; if (yc < 0 || yc >= GRIDN) continue;
                bool face = (dz == -r || dz == r || dy == -r || dy == r);
                int step = face ? 1 : (2 * r);   // interior rows: only dx = ±r
                for (int dx = -r; dx <= r; dx += step) {
                    int xc = cx + dx; if (xc < 0 || xc >= GRIDN) continue;
                    int c = (zc * GRIDN + yc) * GRIDN + xc;
                    unsigned int s = gstart[c], e = gstart[c + 1];
                    for (unsigned int i = s + (unsigned int)tl; i < e; i += 8) {
                        float4 g = gpts[i];
                        float ddx = qx - g.x, ddy = qy - g.y, ddz = qz - g.z;
                        float d2 = fmaf(ddx, ddx, fmaf(ddy, ddy, ddz * ddz));
                        // d2 >= 0 -> raw float bits are order-monotonic; ties -> lowest idx
                        unsigned long long key =
                            ((unsigned long long)__float_as_uint(d2) << 32)
                            | (unsigned long long)__float_as_uint(g.w);
                        if (key < best) { best = key; bestd2 = d2; }
                    }
                    if (step == 0) break;        // r == 0: single cell
                }
            }
        }
    }

    // team-reduce packed key (order-independent, deterministic)
    {
        unsigned long long o;
        o = __shfl_xor(best, 1); if (o < best) best = o;
        o = __shfl_xor(best, 2); if (o < best) best = o;
        o = __shfl_xor(best, 4); if (o < best) best = o;
    }
    const int bidx = (int)(best & 0xFFFFFFFFull);

    // loss terms (all 8 lanes compute identically; only lane0 contributes)
    const float* g = gt + (size_t)bidx * 6;
    float gx = g[0], gy = g[1], gz = g[2];
    float gnx = g[3], gny = g[4], gnz = g[5];
    float pnx = p[3], pny = p[4], pnz = p[5];

    float dx = qx - gx, dy = qy - gy, dz = qz - gz;
    float v1 = dx * dx + dy * dy + dz * dz;

    float pn = sqrtf(pnx * pnx + pny * pny + pnz * pnz);
    float gn = sqrtf(gnx * gnx + gny * gny + gnz * gnz);
    float denom = fmaxf(pn, 1e-4f) * fmaxf(gn, 1e-4f);
    float cosv = (pnx * gnx + pny * gny + pnz * gnz) / denom;
    float v2 = 1.0f - cosv;

    if (tl != 0) { v1 = 0.0f; v2 = 0.0f; }

    #pragma unroll
    for (int off = 32; off > 0; off >>= 1) {
        v1 += __shfl_down(v1, off);
        v2 += __shfl_down(v2, off);
    }
    __shared__ float s1[QBLK / 64];
    __shared__ float s2[QBLK / 64];
    __shared__ int lastFlag;
    int wid = threadIdx.x >> 6;
    if ((threadIdx.x & 63) == 0) { s1[wid] = v1; s2[wid] = v2; }
    __syncthreads();
    if (threadIdx.x == 0) {
        float a = 0.0f, b = 0.0f;
        #pragma unroll
        for (int w = 0; w < QBLK / 64; ++w) { a += s1[w]; b += s2[w]; }
        unsigned long long pk = (unsigned long long)__float_as_uint(a)
                              | ((unsigned long long)__float_as_uint(b) << 32);
        __hip_atomic_store(&bsums[blockIdx.x], pk, __ATOMIC_RELEASE, __HIP_MEMORY_SCOPE_AGENT);
        unsigned int tk = __hip_atomic_fetch_add(counter, 1u, __ATOMIC_ACQ_REL, __HIP_MEMORY_SCOPE_AGENT);
        lastFlag = (tk == NQB - 1) ? 1 : 0;
    }
    __syncthreads();
    if (lastFlag) {
        // final deterministic reduce over 256 block partials (block has 256 threads)
        unsigned long long pk = __hip_atomic_load(&bsums[threadIdx.x],
                                                  __ATOMIC_ACQUIRE, __HIP_MEMORY_SCOPE_AGENT);
        float a = __uint_as_float((unsigned int)(pk & 0xFFFFFFFFull));
        float b = __uint_as_float((unsigned int)(pk >> 32));
        #pragma unroll
        for (int off = 32; off > 0; off >>= 1) {
            a += __shfl_down(a, off);
            b += __shfl_down(b, off);
        }
        __syncthreads();
        if ((threadIdx.x & 63) == 0) { s1[wid] = a; s2[wid] = b; }
        __syncthreads();
        if (threadIdx.x == 0) {
            float fa = 0.0f, fb = 0.0f;
            #pragma unroll
            for (int w = 0; w < QBLK / 64; ++w) { fa += s1[w]; fb += s2[w]; }
            out[0] = fa / (NPRED * 3.0f) + fb / (float)NPRED;
        }
    }
}

extern "C" void kernel_launch(void* const* d_in, const int* in_sizes, int n_in,
                              void* d_out, int out_size, void* d_ws, size_t ws_size,
                              hipStream_t stream) {
    const float* pred_feat = (const float*)d_in[0];
    const float* gt_data   = (const float*)d_in[3];
    float* out = (float*)d_out;

    char* ws = (char*)d_ws;
    unsigned int* gcnt   = (unsigned int*)(ws + 0);
    unsigned int* gofs   = (unsigned int*)(ws + 16384);
    unsigned int* gstart = (unsigned int*)(ws + 32768);
    float4*       gpts   = (float4*)(ws + 49664);
    unsigned long long* bsums = (unsigned long long*)(ws + 573952);
    unsigned int* counter = (unsigned int*)(ws + 576000);

    zero_kernel<<<16, 256, 0, stream>>>(gcnt, gofs, counter);
    hist_kernel<<<NGT / 256, 256, 0, stream>>>(gt_data, gcnt);
    scan_kernel<<<1, 1024, 0, stream>>>(gcnt, gstart);
    scatter_kernel<<<NGT / 256, 256, 0, stream>>>(gt_data, gstart, gofs, gpts);
    query_kernel<<<NQB, QBLK, 0, stream>>>(pred_feat, gt_data, gstart, gpts, bsums, counter, out);
}

// Round 13
// 176.735 us; speedup vs baseline: 1.2183x; 1.2183x over previous
//
#include <hip/hip_runtime.h>
#include <float.h>

#define NPRED 8192
#define NGT   32768
#define GRIDN 32
#define NCELL (GRIDN * GRIDN * GRIDN)     // 32768
#define GBOUND 2.8125f
#define GINV   5.6888890f                 // 1/0.17578125
#define LBW    0.1757f                    // slightly < true cell width (conservative)
#define NRB    256
#define RBW    0.01953125f                // 5/256 exact
#define RBINV  51.2f
#define TAILR2 7.29f                      // 2.7^2
#define TL     16
#define QBLK   256
#define NQB    ((NPRED * TL) / QBLK)      // 512 query blocks

// ws byte offsets
#define OFF_GCNT   0u                     // u32[32768]
#define OFF_GOFS   131072u                // u32[32768]  (contiguous with gcnt for zeroing)
#define OFF_GSTART 262144u                // u32[32769]
#define OFF_RCNT   393224u                // u32[256]
#define OFF_ROFS   394248u                // u32[256]   (contiguous with rcnt)
#define OFF_RSTART 395272u                // u32[257]
#define OFF_GPTS   396304u                // float4[32768] (16B aligned)
#define OFF_RPTS   920592u                // float4[32768]
#define OFF_BSUMS  1444880u               // u64[512]
#define OFF_CNT    1448976u               // u32

__device__ __forceinline__ int cellco(float v) {
    int c = (int)floorf((v + GBOUND) * GINV);
    return min(GRIDN - 1, max(0, c));
}

__global__ void zero_kernel(unsigned int* __restrict__ gbase, unsigned int* __restrict__ rbase,
                            unsigned int* __restrict__ counter) {
    int i = blockIdx.x * 256 + threadIdx.x;
    if (i < 65536) gbase[i] = 0u;                 // gcnt + gofs
    int r = i - 65536;
    if (r >= 0 && r < 512) rbase[r] = 0u;         // rcnt + rofs
    if (i == 0) *counter = 0u;
}

__global__ void hist_kernel(const float* __restrict__ gt, unsigned int* __restrict__ gcnt,
                            unsigned int* __restrict__ rcnt) {
    int j = blockIdx.x * 256 + threadIdx.x;       // < NGT by grid construction
    const float* g = gt + (size_t)j * 6;
    float x = g[0], y = g[1], z = g[2];
    int c = (cellco(z) * GRIDN + cellco(y)) * GRIDN + cellco(x);
    atomicAdd(&gcnt[c], 1u);
    float r = sqrtf(x * x + y * y + z * z);
    atomicAdd(&rcnt[min(NRB - 1, (int)(r * RBINV))], 1u);
}

__global__ __launch_bounds__(1024) void scan_kernel(const unsigned int* __restrict__ gcnt,
                                                    unsigned int* __restrict__ gstart,
                                                    const unsigned int* __restrict__ rcnt,
                                                    unsigned int* __restrict__ rstart) {
    __shared__ unsigned int part[1024];
    const int t = threadIdx.x;
    unsigned int s = 0;
    for (int j = 0; j < 32; ++j) s += gcnt[t * 32 + j];
    part[t] = s;
    __syncthreads();
    for (int off = 1; off < 1024; off <<= 1) {    // Hillis-Steele inclusive
        unsigned int v = (t >= off) ? part[t - off] : 0u;
        __syncthreads();
        part[t] += v;
        __syncthreads();
    }
    unsigned int run = (t > 0) ? part[t - 1] : 0u;
    for (int j = 0; j < 32; ++j) { unsigned int c = gcnt[t * 32 + j]; gstart[t * 32 + j] = run; run += c; }
    if (t == 1023) gstart[NCELL] = run;
    // radius-bin scan by wave 0 (no barriers needed)
    if (t < 64) {
        unsigned int c0 = rcnt[4 * t], c1 = rcnt[4 * t + 1], c2 = rcnt[4 * t + 2], c3 = rcnt[4 * t + 3];
        unsigned int ss = c0 + c1 + c2 + c3;
        unsigned int inc = ss;
        for (int off = 1; off < 64; off <<= 1) { unsigned int v = __shfl_up(inc, off); if (t >= off) inc += v; }
        unsigned int excl = inc - ss;
        rstart[4 * t] = excl; rstart[4 * t + 1] = excl + c0;
        rstart[4 * t + 2] = excl + c0 + c1; rstart[4 * t + 3] = excl + c0 + c1 + c2;
        if (t == 63) rstart[NRB] = inc;
    }
}

__global__ void scatter_kernel(const float* __restrict__ gt,
                               const unsigned int* __restrict__ gstart, unsigned int* __restrict__ gofs,
                               float4* __restrict__ gpts,
                               const unsigned int* __restrict__ rstart, unsigned int* __restrict__ rofs,
                               float4* __restrict__ rpts) {
    int j = blockIdx.x * 256 + threadIdx.x;
    const float* g = gt + (size_t)j * 6;
    float x = g[0], y = g[1], z = g[2];
    float4 v = make_float4(x, y, z, __uint_as_float((unsigned int)j));
    int c = (cellco(z) * GRIDN + cellco(y)) * GRIDN + cellco(x);
    gpts[gstart[c] + atomicAdd(&gofs[c], 1u)] = v;
    float r = sqrtf(x * x + y * y + z * z);
    int rb = min(NRB - 1, (int)(r * RBINV));
    rpts[rstart[rb] + atomicAdd(&rofs[rb], 1u)] = v;
}

__device__ __forceinline__ void scanRange(unsigned int s, unsigned int e, int tl,
                                          const float4* __restrict__ pts,
                                          float qx, float qy, float qz,
                                          unsigned long long& best, float& bestd2) {
    for (unsigned int i = s + (unsigned int)tl; i < e; i += TL) {
        float4 g = pts[i];
        float ddx = qx - g.x, ddy = qy - g.y, ddz = qz - g.z;
        float d2 = fmaf(ddx, ddx, fmaf(ddy, ddy, ddz * ddz));       // >= 0: bits order-monotonic
        unsigned long long key = ((unsigned long long)__float_as_uint(d2) << 32)
                               | (unsigned long long)__float_as_uint(g.w);
        if (key < best) { best = key; bestd2 = d2; }                // ties -> lowest gt idx
    }
}

__global__ __launch_bounds__(QBLK) void query_kernel(const float* __restrict__ pred,
                                                     const float* __restrict__ gt,
                                                     const unsigned int* __restrict__ gstart,
                                                     const float4* __restrict__ gpts,
                                                     const unsigned int* __restrict__ rstart,
                                                     const float4* __restrict__ rpts,
                                                     unsigned long long* __restrict__ bsums,
                                                     unsigned int* __restrict__ counter,
                                                     float* __restrict__ out) {
    const int tid = blockIdx.x * QBLK + threadIdx.x;
    const int q = tid >> 4;
    const int tl = tid & (TL - 1);
    const float* p = pred + (size_t)q * 6;
    const float qx = p[0], qy = p[1], qz = p[2];
    const float r2q = qx * qx + qy * qy + qz * qz;

    unsigned long long best = 0xFFFFFFFFFFFFFFFFull;
    float bestd2 = FLT_MAX;

    if (r2q <= TAILR2) {
        // CORE: fine-grid walk. Query coords are interior (|v| <= 2.7 < 2.8125) -> unclamped.
        const int cx = cellco(qx), cy = cellco(qy), cz = cellco(qz);
        const int x0b = max(0, cx - 1), x1b = min(GRIDN - 1, cx + 1);
        #pragma unroll
        for (int dz = -1; dz <= 1; ++dz) {
            int zc = cz + dz; if (zc < 0 || zc >= GRIDN) continue;
            #pragma unroll
            for (int dy = -1; dy <= 1; ++dy) {
                int yc = cy + dy; if (yc < 0 || yc >= GRIDN) continue;
                int c0 = (zc * GRIDN + yc) * GRIDN + x0b;           // row cells contiguous in x
                scanRange(gstart[c0], gstart[c0 + (x1b - x0b) + 1], tl, gpts, qx, qy, qz, best, bestd2);
            }
        }
        for (int k = 2; ; ++k) {
            float tmin = bestd2;                                    // team-min (16 lanes)
            tmin = fminf(tmin, __shfl_xor(tmin, 1));
            tmin = fminf(tmin, __shfl_xor(tmin, 2));
            tmin = fminf(tmin, __shfl_xor(tmin, 4));
            tmin = fminf(tmin, __shfl_xor(tmin, 8));
            float lb = (float)(k - 1) * LBW;                        // unscanned pts >= (k-1)*width away
            if (tmin < lb * lb * 0.999f) break;
            if (k > 31) break;                                      // box(31) already covered all cells
            int x0 = max(0, cx - k), x1 = min(GRIDN - 1, cx + k);
            for (int dz = -k; dz <= k; ++dz) {
                int zc = cz + dz; if (zc < 0 || zc >= GRIDN) continue;
                for (int dy = -k; dy <= k; ++dy) {
                    int yc = cy + dy; if (yc < 0 || yc >= GRIDN) continue;
                    int c0 = (zc * GRIDN + yc) * GRIDN + x0;        // full-box rescan: redundant but min-idempotent
                    scanRange(gstart[c0], gstart[c0 + (x1 - x0) + 1], tl, gpts, qx, qy, qz, best, bestd2);
                }
            }
        }
    } else {
        // TAIL: radius-sorted band walk, |d(q,g)| >= |rq - rg|
        const float rq = sqrtf(r2q);
        const int rb = min(NRB - 1, (int)(rq * RBINV));
        int k = 16;
        for (;;) {
            int lo = max(0, rb - k), hi = min(NRB - 1, rb + k);
            scanRange(rstart[lo], rstart[hi + 1], tl, rpts, qx, qy, qz, best, bestd2);
            float tmin = bestd2;
            tmin = fminf(tmin, __shfl_xor(tmin, 1));
            tmin = fminf(tmin, __shfl_xor(tmin, 2));
            tmin = fminf(tmin, __shfl_xor(tmin, 4));
            tmin = fminf(tmin, __shfl_xor(tmin, 8));
            bool full = (lo == 0) && (hi == NRB - 1);
            float lbr = 1e18f;
            if (hi < NRB - 1) lbr = fminf(lbr, (float)(hi - rb));
            if (lo > 0)       lbr = fminf(lbr, (float)(rb - lo));
            lbr *= RBW;
            if (full || tmin < lbr * lbr * 0.999f) break;
            k <<= 1;
        }
    }

    // team-reduce packed key (order-independent, deterministic)
    {
        unsigned long long o;
        o = __shfl_xor(best, 1); if (o < best) best = o;
        o = __shfl_xor(best, 2); if (o < best) best = o;
        o = __shfl_xor(best, 4); if (o < best) best = o;
        o = __shfl_xor(best, 8); if (o < best) best = o;
    }
    const int bidx = (int)(best & 0xFFFFFFFFull);

    const float* gg = gt + (size_t)bidx * 6;
    float gx = gg[0], gy = gg[1], gz = gg[2];
    float gnx = gg[3], gny = gg[4], gnz = gg[5];
    float pnx = p[3], pny = p[4], pnz = p[5];

    float dx = qx - gx, dy = qy - gy, dz = qz - gz;
    float v1 = dx * dx + dy * dy + dz * dz;
    float pn = sqrtf(pnx * pnx + pny * pny + pnz * pnz);
    float gn = sqrtf(gnx * gnx + gny * gny + gnz * gnz);
    float denom = fmaxf(pn, 1e-4f) * fmaxf(gn, 1e-4f);
    float v2 = 1.0f - (pnx * gnx + pny * gny + pnz * gnz) / denom;

    __shared__ float2 teamv[QBLK / TL];           // 16 teams
    __shared__ int lastFlag;
    if (tl == 0) teamv[threadIdx.x >> 4] = make_float2(v1, v2);
    __syncthreads();
    if (threadIdx.x == 0) {
        float a = 0.0f, b = 0.0f;
        #pragma unroll
        for (int w = 0; w < QBLK / TL; ++w) { a += teamv[w].x; b += teamv[w].y; }
        unsigned long long pk = (unsigned long long)__float_as_uint(a)
                              | ((unsigned long long)__float_as_uint(b) << 32);
        __hip_atomic_store(&bsums[blockIdx.x], pk, __ATOMIC_RELEASE, __HIP_MEMORY_SCOPE_AGENT);
        unsigned int tk = __hip_atomic_fetch_add(counter, 1u, __ATOMIC_ACQ_REL, __HIP_MEMORY_SCOPE_AGENT);
        lastFlag = (tk == NQB - 1) ? 1 : 0;
    }
    __syncthreads();
    if (lastFlag) {
        float a = 0.0f, b = 0.0f;
        for (int e = threadIdx.x; e < NQB; e += QBLK) {             // 2 entries/thread, fixed order
            unsigned long long pk = __hip_atomic_load(&bsums[e], __ATOMIC_ACQUIRE, __HIP_MEMORY_SCOPE_AGENT);
            a += __uint_as_float((unsigned int)(pk & 0xFFFFFFFFull));
            b += __uint_as_float((unsigned int)(pk >> 32));
        }
        #pragma unroll
        for (int off = 32; off > 0; off >>= 1) {
            a += __shfl_down(a, off);
            b += __shfl_down(b, off);
        }
        __shared__ float s1[QBLK / 64], s2[QBLK / 64];
        int wid = threadIdx.x >> 6;
        if ((threadIdx.x & 63) == 0) { s1[wid] = a; s2[wid] = b; }
        __syncthreads();
        if (threadIdx.x == 0) {
            float fa = 0.0f, fb = 0.0f;
            #pragma unroll
            for (int w = 0; w < QBLK / 64; ++w) { fa += s1[w]; fb += s2[w]; }
            out[0] = fa / (NPRED * 3.0f) + fb / (float)NPRED;
        }
    }
}

extern "C" void kernel_launch(void* const* d_in, const int* in_sizes, int n_in,
                              void* d_out, int out_size, void* d_ws, size_t ws_size,
                              hipStream_t stream) {
    const float* pred_feat = (const float*)d_in[0];
    const float* gt_data   = (const float*)d_in[3];
    float* out = (float*)d_out;

    char* ws = (char*)d_ws;
    unsigned int* gcnt   = (unsigned int*)(ws + OFF_GCNT);
    unsigned int* gofs   = (unsigned int*)(ws + OFF_GOFS);
    unsigned int* gstart = (unsigned int*)(ws + OFF_GSTART);
    unsigned int* rcnt   = (unsigned int*)(ws + OFF_RCNT);
    unsigned int* rofs   = (unsigned int*)(ws + OFF_ROFS);
    unsigned int* rstart = (unsigned int*)(ws + OFF_RSTART);
    float4*       gpts   = (float4*)(ws + OFF_GPTS);
    float4*       rpts   = (float4*)(ws + OFF_RPTS);
    unsigned long long* bsums = (unsigned long long*)(ws + OFF_BSUMS);
    unsigned int* counter = (unsigned int*)(ws + OFF_CNT);

    zero_kernel<<<258, 256, 0, stream>>>(gcnt, rcnt, counter);
    hist_kernel<<<NGT / 256, 256, 0, stream>>>(gt_data, gcnt, rcnt);
    scan_kernel<<<1, 1024, 0, stream>>>(gcnt, gstart, rcnt, rstart);
    scatter_kernel<<<NGT / 256, 256, 0, stream>>>(gt_data, gstart, gofs, gpts, rstart, rofs, rpts);
    query_kernel<<<NQB, QBLK, 0, stream>>>(pred_feat, gt_data, gstart, gpts, rstart, rpts,
                                           bsums, counter, out);
}